// Round 18
// baseline (50.840 us; speedup 1.0000x reference)
//
#include <hip/hip_runtime.h>
#include <hip/hip_bf16.h>

// Sizes (fixed by the reference)
#define BB 64
#define AA 128
#define FF 32
#define HH 64
#define GXDIM 12   // k2 blocks per b: 768 total = 3 blocks/CU (LDS-limited)

// R18 = R13 byte-identical EXCEPT k2's group loop runs TWICE (idempotent
// writes) -- a timing probe: dur - 38us = k2 compute time. Keep-alive asm
// prevents the compiler from eliding the second pass.
#define NREP 2

typedef float  f32x4  __attribute__((ext_vector_type(4)));
typedef float  f32x16 __attribute__((ext_vector_type(16)));
typedef __bf16 bf16x8 __attribute__((ext_vector_type(8)));
typedef unsigned int uint4v __attribute__((ext_vector_type(4)));

// ws layout (float offsets)
#define OFF_HIP   0          // hi_p fp32 [B*A][64]  (pair_b1 folded in)
#define OFF_HJ    524288     // hj   fp32 [B*A][64]
#define OFF_BU    1048576    // base_u [B*A]
#define OFF_UTIL  1056768    // util [B*A]
#define OFF_W2FH  1064960    // W2 frag hi: [8 fid][64 lane][8 ushort] = 8 KB
#define OFF_W2FL  1067008    // W2 frag lo
#define OFF_JLIST 1069056    // active-index list [B][128] int
#define OFF_JCNT  1077248    // [B] int

static __device__ __forceinline__ unsigned short f2b_rne(float x) {
    __hip_bfloat16 h = __float2bfloat16(x);
    return __builtin_bit_cast(unsigned short, h);
}
static __device__ __forceinline__ float b2f(unsigned short u) {
    unsigned v = ((unsigned)u) << 16;
    return __builtin_bit_cast(float, v);
}

// ---------------- Kernel 1: features + active-list + W2 frag split --------
__global__ __launch_bounds__(64)
void ddc_features(const float* __restrict__ X, const int* __restrict__ mask,
                  const float* __restrict__ bW1, const float* __restrict__ bb1,
                  const float* __restrict__ bW2, const float* __restrict__ bb2,
                  const float* __restrict__ bW3, const float* __restrict__ bb3,
                  const float* __restrict__ pW1, const float* __restrict__ pb1,
                  const float* __restrict__ pW2,
                  float* __restrict__ hi_p, float* __restrict__ hj,
                  float* __restrict__ base_u,
                  unsigned short* __restrict__ W2fh,
                  unsigned short* __restrict__ W2fl,
                  int* __restrict__ jlist, int* __restrict__ jcnt) {
    const int a = blockIdx.x, b = blockIdx.y, lane = threadIdx.x;
    const int row = b * AA + a;

    // X row is wave-uniform -> scalar loads
    const float* __restrict__ x = X + row * FF;
    float xr[FF];
#pragma unroll
    for (int f = 0; f < FF; ++f) xr[f] = x[f];

    float vhi = pb1[lane];      // fold pair_b1 into hi
    float vhj = 0.f;
    float v1  = bb1[lane];
#pragma unroll
    for (int f = 0; f < FF; ++f) {
        vhi = fmaf(xr[f], pW1[f * HH + lane], vhi);
        vhj = fmaf(xr[f], pW1[(FF + f) * HH + lane], vhj);
        v1  = fmaf(xr[f], bW1[f * HH + lane], v1);
    }
    v1 = fmaxf(v1, 0.f);

    // hb2 = relu(hb1 @ bW2 + bb2): broadcast hb1 across lanes via shuffles
    float v2 = bb2[lane];
#pragma unroll
    for (int k = 0; k < HH; ++k) {
        float hk = __shfl(v1, k);
        v2 = fmaf(hk, bW2[k * HH + lane], v2);
    }
    v2 = fmaxf(v2, 0.f);

    float bu = v2 * bW3[lane];
#pragma unroll
    for (int off = 32; off; off >>= 1) bu += __shfl_xor(bu, off);

    hi_p[row * HH + lane] = vhi;
    hj  [row * HH + lane] = vhj;
    if (lane == 0) base_u[row] = bu + bb3[0];

    // one block per b builds the compacted active-index list
    if (a == 0) {
        int base0 = 0;
#pragma unroll
        for (int hlf = 0; hlf < 2; ++hlf) {
            int idx = hlf * 64 + lane;
            int m = mask[b * AA + idx];
            unsigned long long bal = __ballot(m != 0);
            int pos = __popcll(bal & ((1ull << lane) - 1ull));
            if (m) jlist[b * AA + base0 + pos] = idx;
            base0 += (int)__popcll(bal);
        }
        if (lane == 0) jcnt[b] = base0;
    }

    // one block writes W2 hi/lo in MFMA B-fragment order:
    // fid = nt*4+ks; lane supplies col n = nt*32+(lane&31),
    // k = ks*16 + (lane>>5)*8 + e  (matches mfma_f32_32x32x16_bf16 B layout)
    if (a == 1 && b == 0) {
        const int col = lane & 31, half = lane >> 5;
#pragma unroll
        for (int fid = 0; fid < 8; ++fid) {
            const int nt = fid >> 2, ks = fid & 3;
            const int n = nt * 32 + col;
            const int ko = ks * 16 + half * 8;
#pragma unroll
            for (int e = 0; e < 8; ++e) {
                float wv = pW2[(ko + e) * HH + n];
                unsigned short uh = f2b_rne(wv);
                W2fh[(fid * 64 + lane) * 8 + e] = uh;
                W2fl[(fid * 64 + lane) * 8 + e] = f2b_rne(wv - b2f(uh));
            }
        }
    }
}

// ---------------- Kernel 2: pairwise MLP via split-bf16 MFMA --------------
// R13 structure (B-frags in LDS, 3 waves/SIMD, persistent grid, compacted j,
// anti-LICM zofs). PROBE: group loop runs NREP=2 times, idempotent writes.
#define SPLIT_PAIR(pa, pb, outh, outl)                                   \
    {   unsigned ua = __builtin_bit_cast(unsigned, pa);                  \
        unsigned ub = __builtin_bit_cast(unsigned, pb);                  \
        outh = (ua >> 16) | (ub & 0xFFFF0000u);                          \
        float ra = pa - __builtin_bit_cast(float, ua & 0xFFFF0000u);     \
        float rb = pb - __builtin_bit_cast(float, ub & 0xFFFF0000u);     \
        unsigned va = __builtin_bit_cast(unsigned, ra);                  \
        unsigned vb = __builtin_bit_cast(unsigned, rb);                  \
        outl = (va >> 16) | (vb & 0xFFFF0000u); }

__global__ __launch_bounds__(256, 3)
void ddc_pairs_mfma(const float* __restrict__ hi_p, const float* __restrict__ hj,
                    const float* __restrict__ base_u,
                    const int* __restrict__ jlist, const int* __restrict__ jcnt,
                    const unsigned short* __restrict__ W2fh,
                    const unsigned short* __restrict__ W2fl,
                    const float* __restrict__ pb2, const float* __restrict__ pW3,
                    const float* __restrict__ pb3, float* __restrict__ util) {
    __shared__ float  sHJ[AA][HH + 4];   // 34816 B
    __shared__ uint4v sBH[512];          // 8192 B  (W2 hi frags)
    __shared__ uint4v sBL[512];          // 8192 B  (W2 lo frags)

    const int t  = threadIdx.x;
    const int gx = blockIdx.x;            // 0..GXDIM-1
    const int b  = blockIdx.y;
    const int cnt = jcnt[b];
    const int ngroups = (cnt + 3) >> 2;   // groups of 4 i-slots (1 per wave)
    if (gx >= ngroups) return;            // idle block: exit BEFORE staging

    const int l = t & 63, wid = t >> 6;
    const int col = l & 31, half = l >> 5;

    // stage B-fragments into LDS (coalesced uint4v)
    {
        const uint4v* __restrict__ gbh = (const uint4v*)W2fh;
        const uint4v* __restrict__ gbl = (const uint4v*)W2fl;
        sBH[t]       = gbh[t];
        sBH[t + 256] = gbh[t + 256];
        sBL[t]       = gbl[t];
        sBL[t + 256] = gbl[t + 256];
    }

    // stage COMPACTED hj rows for this b (gather via jlist); zero-fill tail
    {
        const int r = t >> 1, hf = t & 1;
        f32x4* dst = (f32x4*)&sHJ[r][hf * 32];
        if (r < cnt) {
            const int jr = jlist[b * AA + r];
            const f32x4* __restrict__ src =
                (const f32x4*)(hj + (b * AA + jr) * HH + hf * 32);
#pragma unroll
            for (int q = 0; q < 8; ++q) dst[q] = src[q];
        } else {
#pragma unroll
            for (int q = 0; q < 8; ++q) dst[q] = (f32x4)0.f;
        }
    }

    __syncthreads();

    const float b2v0 = pb2[col], b2v1 = pb2[32 + col];
    const float w3v0 = pW3[col], w3v1 = pW3[32 + col];
    const float b3s  = pb3[0] * (1.f / 32.f);   // b3 spread over 32 col-lanes

    const int ntiles = (cnt + 31) >> 5;   // compacted j-tiles

    for (int rep = 0; rep < NREP; ++rep) {
    for (int g = gx; g < ngroups; g += GXDIM) {
        const int slot = g * 4 + wid;
        if (slot >= cnt) continue;            // tail (wave-uniform)
        const int i = __builtin_amdgcn_readfirstlane(jlist[b * AA + slot]);

        // hi row slice for this lane's k-chunks (32 floats)
        const float* __restrict__ hp = hi_p + (b * AA + i) * HH;
        f32x4 yv[8];
#pragma unroll
        for (int ks = 0; ks < 4; ++ks) {
            const int ko = ks * 16 + half * 8;
            yv[2 * ks]     = *(const f32x4*)(hp + ko);
            yv[2 * ks + 1] = *(const f32x4*)(hp + ko + 4);
        }

        float tsum = 0.f;
        for (int jt = 0; jt < ntiles; ++jt) {
            // opaque zero: makes B-frag LDS addresses loop-variant so LICM
            // cannot hoist the 16 ds_reads into long-lived registers
            unsigned zofs = 0;
            asm volatile("" : "+v"(zofs));

            f32x16 acc0 = b2v0, acc1 = b2v1;   // fold pb2 bias into C init
            const int jj = jt * 32 + col;

#define KSTEP(ks)                                                           \
            {   const int ko = (ks) * 16 + half * 8;                        \
                uint4v bh0 = sBH[(ks) * 64 + l + zofs];                     \
                uint4v bl0 = sBL[(ks) * 64 + l + zofs];                     \
                uint4v bh1 = sBH[(4 + (ks)) * 64 + l + zofs];               \
                uint4v bl1 = sBL[(4 + (ks)) * 64 + l + zofs];               \
                f32x4 x0 = *(const f32x4*)&sHJ[jj][ko];                     \
                f32x4 x1 = *(const f32x4*)&sHJ[jj][ko + 4];                 \
                f32x4 y0 = yv[2 * (ks)], y1 = yv[2 * (ks) + 1];             \
                float h0 = fmaxf(x0[0] + y0[0], 0.f);                       \
                float h1 = fmaxf(x0[1] + y0[1], 0.f);                       \
                float h2 = fmaxf(x0[2] + y0[2], 0.f);                       \
                float h3 = fmaxf(x0[3] + y0[3], 0.f);                       \
                float h4 = fmaxf(x1[0] + y1[0], 0.f);                       \
                float h5 = fmaxf(x1[1] + y1[1], 0.f);                       \
                float h6 = fmaxf(x1[2] + y1[2], 0.f);                       \
                float h7 = fmaxf(x1[3] + y1[3], 0.f);                       \
                unsigned a01, a23, a45, a67, c01, c23, c45, c67;            \
                SPLIT_PAIR(h0, h1, a01, c01)                                \
                SPLIT_PAIR(h2, h3, a23, c23)                                \
                SPLIT_PAIR(h4, h5, a45, c45)                                \
                SPLIT_PAIR(h6, h7, a67, c67)                                \
                uint4v ahv = {a01, a23, a45, a67};                          \
                uint4v alv = {c01, c23, c45, c67};                          \
                bf16x8 ah = __builtin_bit_cast(bf16x8, ahv);                \
                bf16x8 al = __builtin_bit_cast(bf16x8, alv);                \
                acc0 = __builtin_amdgcn_mfma_f32_32x32x16_bf16(             \
                    al, __builtin_bit_cast(bf16x8, bh0), acc0, 0, 0, 0);    \
                acc1 = __builtin_amdgcn_mfma_f32_32x32x16_bf16(             \
                    al, __builtin_bit_cast(bf16x8, bh1), acc1, 0, 0, 0);    \
                acc0 = __builtin_amdgcn_mfma_f32_32x32x16_bf16(             \
                    ah, __builtin_bit_cast(bf16x8, bl0), acc0, 0, 0, 0);    \
                acc1 = __builtin_amdgcn_mfma_f32_32x32x16_bf16(             \
                    ah, __builtin_bit_cast(bf16x8, bl1), acc1, 0, 0, 0);    \
                acc0 = __builtin_amdgcn_mfma_f32_32x32x16_bf16(             \
                    ah, __builtin_bit_cast(bf16x8, bh0), acc0, 0, 0, 0);    \
                acc1 = __builtin_amdgcn_mfma_f32_32x32x16_bf16(             \
                    ah, __builtin_bit_cast(bf16x8, bh1), acc1, 0, 0, 0);    \
            }
            KSTEP(0)
            KSTEP(1)
            KSTEP(2)
            KSTEP(3)
#undef KSTEP

            // epilogue: W3 contraction; SELECT-zero invalid rows (tail or
            // diagonal slot) -- never multiply (garbage may be non-finite)
#pragma unroll
            for (int r = 0; r < 16; ++r) {
                const int rrow = (r & 3) + 8 * (r >> 2) + 4 * half;
                const int jg = jt * 32 + rrow;
                float v = fmaxf(acc0[r], 0.f) * w3v0 +
                          fmaxf(acc1[r], 0.f) * w3v1 + b3s;
                const bool valid = (jg < cnt) && (jg != slot);
                tsum += valid ? v : 0.f;
            }
        }
#pragma unroll
        for (int off = 32; off; off >>= 1) tsum += __shfl_xor(tsum, off);
        asm volatile("" :: "v"(tsum));        // keep rep's work alive
        if (l == 0) util[b * AA + i] = base_u[b * AA + i] + tsum;
    }
    }
}

// ---------------- Kernel 3: per-b masked softmax over A=128 ---------------
__global__ __launch_bounds__(64)
void ddc_softmax(const float* __restrict__ util, const int* __restrict__ mask,
                 float* __restrict__ out) {
    const int b = blockIdx.x, lane = threadIdx.x;
    const int r0 = b * AA + lane, r1 = r0 + 64;
    const float u0 = (mask[r0] != 0) ? util[r0] : -1e9f;
    const float u1 = (mask[r1] != 0) ? util[r1] : -1e9f;

    float m = fmaxf(u0, u1);
#pragma unroll
    for (int off = 32; off; off >>= 1) m = fmaxf(m, __shfl_xor(m, off));

    const float e0 = __expf(u0 - m);
    const float e1 = __expf(u1 - m);
    float s = e0 + e1;
#pragma unroll
    for (int off = 32; off; off >>= 1) s += __shfl_xor(s, off);

    const float inv = 1.f / s;
    out[r0] = e0 * inv;
    out[r1] = e1 * inv;
}

extern "C" void kernel_launch(void* const* d_in, const int* in_sizes, int n_in,
                              void* d_out, int out_size, void* d_ws, size_t ws_size,
                              hipStream_t stream) {
    const float* X    = (const float*)d_in[0];
    const int*   mask = (const int*)  d_in[1];
    const float* bW1  = (const float*)d_in[2];
    const float* bb1  = (const float*)d_in[3];
    const float* bW2  = (const float*)d_in[4];
    const float* bb2  = (const float*)d_in[5];
    const float* bW3  = (const float*)d_in[6];
    const float* bb3  = (const float*)d_in[7];
    const float* pW1  = (const float*)d_in[8];
    const float* pb1  = (const float*)d_in[9];
    const float* pW2  = (const float*)d_in[10];
    const float* pb2  = (const float*)d_in[11];
    const float* pW3  = (const float*)d_in[12];
    const float* pb3  = (const float*)d_in[13];

    float* ws    = (float*)d_ws;
    float* hi_p  = ws + OFF_HIP;
    float* hjW   = ws + OFF_HJ;
    float* baseu = ws + OFF_BU;
    float* util  = ws + OFF_UTIL;
    unsigned short* W2fh = (unsigned short*)(ws + OFF_W2FH);
    unsigned short* W2fl = (unsigned short*)(ws + OFF_W2FL);
    int*   jlist = (int*)(ws + OFF_JLIST);
    int*   jcnt  = (int*)(ws + OFF_JCNT);

    float* out = (float*)d_out;

    dim3 g1(AA, BB);
    ddc_features<<<g1, 64, 0, stream>>>(X, mask, bW1, bb1, bW2, bb2, bW3, bb3,
                                        pW1, pb1, pW2,
                                        hi_p, hjW, baseu, W2fh, W2fl,
                                        jlist, jcnt);
    dim3 g2(GXDIM, BB);
    ddc_pairs_mfma<<<g2, 256, 0, stream>>>(hi_p, hjW, baseu, jlist, jcnt,
                                           W2fh, W2fl, pb2, pW3, pb3, util);
    ddc_softmax<<<BB, 64, 0, stream>>>(util, mask, out);
}

// Round 19
// 36.234 us; speedup vs baseline: 1.4031x; 1.4031x over previous
//
#include <hip/hip_runtime.h>
#include <hip/hip_bf16.h>

// Sizes (fixed by the reference)
#define BB 64
#define AA 128
#define FF 32
#define HH 64
#define GXDIM 12   // k2 blocks per b: 768 total = 3 blocks/CU (LDS-limited)

typedef float  f32x4  __attribute__((ext_vector_type(4)));
typedef float  f32x16 __attribute__((ext_vector_type(16)));
typedef __bf16 bf16x8 __attribute__((ext_vector_type(8)));
typedef unsigned int uint4v __attribute__((ext_vector_type(4)));

// ws layout (float offsets)
#define OFF_HIP   0          // hi_p fp32 [B*A][64]  (pair_b1 folded in)
#define OFF_HJ    524288     // hj   fp32 [B*A][64]
#define OFF_BU    1048576    // base_u [B*A]
#define OFF_UTIL  1056768    // util [B*A]
#define OFF_W2FH  1064960    // W2 frag hi: [8 fid][64 lane][8 ushort] = 8 KB
#define OFF_W2FL  1067008    // W2 frag lo
#define OFF_JLIST 1069056    // active-index list [B][128] int
#define OFF_JCNT  1077248    // [B] int

static __device__ __forceinline__ unsigned short f2b_rne(float x) {
    __hip_bfloat16 h = __float2bfloat16(x);
    return __builtin_bit_cast(unsigned short, h);
}
static __device__ __forceinline__ float b2f(unsigned short u) {
    unsigned v = ((unsigned)u) << 16;
    return __builtin_bit_cast(float, v);
}

// ---------------- Kernel 1: features + active-list + W2 frag split --------
__global__ __launch_bounds__(64)
void ddc_features(const float* __restrict__ X, const int* __restrict__ mask,
                  const float* __restrict__ bW1, const float* __restrict__ bb1,
                  const float* __restrict__ bW2, const float* __restrict__ bb2,
                  const float* __restrict__ bW3, const float* __restrict__ bb3,
                  const float* __restrict__ pW1, const float* __restrict__ pb1,
                  const float* __restrict__ pW2,
                  float* __restrict__ hi_p, float* __restrict__ hj,
                  float* __restrict__ base_u,
                  unsigned short* __restrict__ W2fh,
                  unsigned short* __restrict__ W2fl,
                  int* __restrict__ jlist, int* __restrict__ jcnt) {
    const int a = blockIdx.x, b = blockIdx.y, lane = threadIdx.x;
    const int row = b * AA + a;

    // X row is wave-uniform -> scalar loads
    const float* __restrict__ x = X + row * FF;
    float xr[FF];
#pragma unroll
    for (int f = 0; f < FF; ++f) xr[f] = x[f];

    float vhi = pb1[lane];      // fold pair_b1 into hi
    float vhj = 0.f;
    float v1  = bb1[lane];
#pragma unroll
    for (int f = 0; f < FF; ++f) {
        vhi = fmaf(xr[f], pW1[f * HH + lane], vhi);
        vhj = fmaf(xr[f], pW1[(FF + f) * HH + lane], vhj);
        v1  = fmaf(xr[f], bW1[f * HH + lane], v1);
    }
    v1 = fmaxf(v1, 0.f);

    // hb2 = relu(hb1 @ bW2 + bb2): broadcast hb1 across lanes via shuffles
    float v2 = bb2[lane];
#pragma unroll
    for (int k = 0; k < HH; ++k) {
        float hk = __shfl(v1, k);
        v2 = fmaf(hk, bW2[k * HH + lane], v2);
    }
    v2 = fmaxf(v2, 0.f);

    float bu = v2 * bW3[lane];
#pragma unroll
    for (int off = 32; off; off >>= 1) bu += __shfl_xor(bu, off);

    hi_p[row * HH + lane] = vhi;
    hj  [row * HH + lane] = vhj;
    if (lane == 0) base_u[row] = bu + bb3[0];

    // one block per b builds the compacted active-index list
    if (a == 0) {
        int base0 = 0;
#pragma unroll
        for (int hlf = 0; hlf < 2; ++hlf) {
            int idx = hlf * 64 + lane;
            int m = mask[b * AA + idx];
            unsigned long long bal = __ballot(m != 0);
            int pos = __popcll(bal & ((1ull << lane) - 1ull));
            if (m) jlist[b * AA + base0 + pos] = idx;
            base0 += (int)__popcll(bal);
        }
        if (lane == 0) jcnt[b] = base0;
    }

    // one block writes W2 hi/lo in MFMA B-fragment order:
    // fid = nt*4+ks; lane supplies col n = nt*32+(lane&31),
    // k = ks*16 + (lane>>5)*8 + e  (matches mfma_f32_32x32x16_bf16 B layout)
    if (a == 1 && b == 0) {
        const int col = lane & 31, half = lane >> 5;
#pragma unroll
        for (int fid = 0; fid < 8; ++fid) {
            const int nt = fid >> 2, ks = fid & 3;
            const int n = nt * 32 + col;
            const int ko = ks * 16 + half * 8;
#pragma unroll
            for (int e = 0; e < 8; ++e) {
                float wv = pW2[(ko + e) * HH + n];
                unsigned short uh = f2b_rne(wv);
                W2fh[(fid * 64 + lane) * 8 + e] = uh;
                W2fl[(fid * 64 + lane) * 8 + e] = f2b_rne(wv - b2f(uh));
            }
        }
    }
}

// ---------------- Kernel 2: pairwise MLP via 2-term split-bf16 MFMA -------
// R19 = R13 skeleton; KSTEP changed 3-term -> 2-term: A = single RNE bf16
// (error ~h*2^-9), B = precomputed hi/lo split. 16 MFMA/jt (was 24) and
// h-gen drops the SPLIT_PAIR remainder chain. All else identical to R13.
__global__ __launch_bounds__(256, 3)
void ddc_pairs_mfma(const float* __restrict__ hi_p, const float* __restrict__ hj,
                    const float* __restrict__ base_u,
                    const int* __restrict__ jlist, const int* __restrict__ jcnt,
                    const unsigned short* __restrict__ W2fh,
                    const unsigned short* __restrict__ W2fl,
                    const float* __restrict__ pb2, const float* __restrict__ pW3,
                    const float* __restrict__ pb3, float* __restrict__ util) {
    __shared__ float  sHJ[AA][HH + 4];   // 34816 B
    __shared__ uint4v sBH[512];          // 8192 B  (W2 hi frags)
    __shared__ uint4v sBL[512];          // 8192 B  (W2 lo frags)

    const int t  = threadIdx.x;
    const int gx = blockIdx.x;            // 0..GXDIM-1
    const int b  = blockIdx.y;
    const int cnt = jcnt[b];
    const int ngroups = (cnt + 3) >> 2;   // groups of 4 i-slots (1 per wave)
    if (gx >= ngroups) return;            // idle block: exit BEFORE staging

    const int l = t & 63, wid = t >> 6;
    const int col = l & 31, half = l >> 5;

    // stage B-fragments into LDS (coalesced uint4v)
    {
        const uint4v* __restrict__ gbh = (const uint4v*)W2fh;
        const uint4v* __restrict__ gbl = (const uint4v*)W2fl;
        sBH[t]       = gbh[t];
        sBH[t + 256] = gbh[t + 256];
        sBL[t]       = gbl[t];
        sBL[t + 256] = gbl[t + 256];
    }

    // stage COMPACTED hj rows for this b (gather via jlist); zero-fill tail
    {
        const int r = t >> 1, hf = t & 1;
        f32x4* dst = (f32x4*)&sHJ[r][hf * 32];
        if (r < cnt) {
            const int jr = jlist[b * AA + r];
            const f32x4* __restrict__ src =
                (const f32x4*)(hj + (b * AA + jr) * HH + hf * 32);
#pragma unroll
            for (int q = 0; q < 8; ++q) dst[q] = src[q];
        } else {
#pragma unroll
            for (int q = 0; q < 8; ++q) dst[q] = (f32x4)0.f;
        }
    }

    __syncthreads();

    const float b2v0 = pb2[col], b2v1 = pb2[32 + col];
    const float w3v0 = pW3[col], w3v1 = pW3[32 + col];
    const float b3s  = pb3[0] * (1.f / 32.f);   // b3 spread over 32 col-lanes

    const int ntiles = (cnt + 31) >> 5;   // compacted j-tiles

    for (int g = gx; g < ngroups; g += GXDIM) {
        const int slot = g * 4 + wid;
        if (slot >= cnt) continue;            // tail (wave-uniform)
        const int i = __builtin_amdgcn_readfirstlane(jlist[b * AA + slot]);

        // hi row slice for this lane's k-chunks (32 floats)
        const float* __restrict__ hp = hi_p + (b * AA + i) * HH;
        f32x4 yv[8];
#pragma unroll
        for (int ks = 0; ks < 4; ++ks) {
            const int ko = ks * 16 + half * 8;
            yv[2 * ks]     = *(const f32x4*)(hp + ko);
            yv[2 * ks + 1] = *(const f32x4*)(hp + ko + 4);
        }

        float tsum = 0.f;
        for (int jt = 0; jt < ntiles; ++jt) {
            // opaque zero: makes B-frag LDS addresses loop-variant so LICM
            // cannot hoist the 16 ds_reads into long-lived registers
            unsigned zofs = 0;
            asm volatile("" : "+v"(zofs));

            f32x16 acc0 = b2v0, acc1 = b2v1;   // fold pb2 bias into C init
            const int jj = jt * 32 + col;

#define KSTEP(ks)                                                           \
            {   const int ko = (ks) * 16 + half * 8;                        \
                uint4v bh0 = sBH[(ks) * 64 + l + zofs];                     \
                uint4v bl0 = sBL[(ks) * 64 + l + zofs];                     \
                uint4v bh1 = sBH[(4 + (ks)) * 64 + l + zofs];               \
                uint4v bl1 = sBL[(4 + (ks)) * 64 + l + zofs];               \
                f32x4 x0 = *(const f32x4*)&sHJ[jj][ko];                     \
                f32x4 x1 = *(const f32x4*)&sHJ[jj][ko + 4];                 \
                f32x4 y0 = yv[2 * (ks)], y1 = yv[2 * (ks) + 1];             \
                float h0 = fmaxf(x0[0] + y0[0], 0.f);                       \
                float h1 = fmaxf(x0[1] + y0[1], 0.f);                       \
                float h2 = fmaxf(x0[2] + y0[2], 0.f);                       \
                float h3 = fmaxf(x0[3] + y0[3], 0.f);                       \
                float h4 = fmaxf(x1[0] + y1[0], 0.f);                       \
                float h5 = fmaxf(x1[1] + y1[1], 0.f);                       \
                float h6 = fmaxf(x1[2] + y1[2], 0.f);                       \
                float h7 = fmaxf(x1[3] + y1[3], 0.f);                       \
                unsigned a01 = (unsigned)f2b_rne(h0) |                      \
                               ((unsigned)f2b_rne(h1) << 16);               \
                unsigned a23 = (unsigned)f2b_rne(h2) |                      \
                               ((unsigned)f2b_rne(h3) << 16);               \
                unsigned a45 = (unsigned)f2b_rne(h4) |                      \
                               ((unsigned)f2b_rne(h5) << 16);               \
                unsigned a67 = (unsigned)f2b_rne(h6) |                      \
                               ((unsigned)f2b_rne(h7) << 16);               \
                uint4v ahv = {a01, a23, a45, a67};                          \
                bf16x8 av = __builtin_bit_cast(bf16x8, ahv);                \
                acc0 = __builtin_amdgcn_mfma_f32_32x32x16_bf16(             \
                    av, __builtin_bit_cast(bf16x8, bh0), acc0, 0, 0, 0);    \
                acc1 = __builtin_amdgcn_mfma_f32_32x32x16_bf16(             \
                    av, __builtin_bit_cast(bf16x8, bh1), acc1, 0, 0, 0);    \
                acc0 = __builtin_amdgcn_mfma_f32_32x32x16_bf16(             \
                    av, __builtin_bit_cast(bf16x8, bl0), acc0, 0, 0, 0);    \
                acc1 = __builtin_amdgcn_mfma_f32_32x32x16_bf16(             \
                    av, __builtin_bit_cast(bf16x8, bl1), acc1, 0, 0, 0);    \
            }
            KSTEP(0)
            KSTEP(1)
            KSTEP(2)
            KSTEP(3)
#undef KSTEP

            // epilogue: W3 contraction; SELECT-zero invalid rows (tail or
            // diagonal slot) -- never multiply (garbage may be non-finite)
#pragma unroll
            for (int r = 0; r < 16; ++r) {
                const int rrow = (r & 3) + 8 * (r >> 2) + 4 * half;
                const int jg = jt * 32 + rrow;
                float v = fmaxf(acc0[r], 0.f) * w3v0 +
                          fmaxf(acc1[r], 0.f) * w3v1 + b3s;
                const bool valid = (jg < cnt) && (jg != slot);
                tsum += valid ? v : 0.f;
            }
        }
#pragma unroll
        for (int off = 32; off; off >>= 1) tsum += __shfl_xor(tsum, off);
        if (l == 0) util[b * AA + i] = base_u[b * AA + i] + tsum;
    }
}

// ---------------- Kernel 3: per-b masked softmax over A=128 ---------------
__global__ __launch_bounds__(64)
void ddc_softmax(const float* __restrict__ util, const int* __restrict__ mask,
                 float* __restrict__ out) {
    const int b = blockIdx.x, lane = threadIdx.x;
    const int r0 = b * AA + lane, r1 = r0 + 64;
    const float u0 = (mask[r0] != 0) ? util[r0] : -1e9f;
    const float u1 = (mask[r1] != 0) ? util[r1] : -1e9f;

    float m = fmaxf(u0, u1);
#pragma unroll
    for (int off = 32; off; off >>= 1) m = fmaxf(m, __shfl_xor(m, off));

    const float e0 = __expf(u0 - m);
    const float e1 = __expf(u1 - m);
    float s = e0 + e1;
#pragma unroll
    for (int off = 32; off; off >>= 1) s += __shfl_xor(s, off);

    const float inv = 1.f / s;
    out[r0] = e0 * inv;
    out[r1] = e1 * inv;
}

extern "C" void kernel_launch(void* const* d_in, const int* in_sizes, int n_in,
                              void* d_out, int out_size, void* d_ws, size_t ws_size,
                              hipStream_t stream) {
    const float* X    = (const float*)d_in[0];
    const int*   mask = (const int*)  d_in[1];
    const float* bW1  = (const float*)d_in[2];
    const float* bb1  = (const float*)d_in[3];
    const float* bW2  = (const float*)d_in[4];
    const float* bb2  = (const float*)d_in[5];
    const float* bW3  = (const float*)d_in[6];
    const float* bb3  = (const float*)d_in[7];
    const float* pW1  = (const float*)d_in[8];
    const float* pb1  = (const float*)d_in[9];
    const float* pW2  = (const float*)d_in[10];
    const float* pb2  = (const float*)d_in[11];
    const float* pW3  = (const float*)d_in[12];
    const float* pb3  = (const float*)d_in[13];

    float* ws    = (float*)d_ws;
    float* hi_p  = ws + OFF_HIP;
    float* hjW   = ws + OFF_HJ;
    float* baseu = ws + OFF_BU;
    float* util  = ws + OFF_UTIL;
    unsigned short* W2fh = (unsigned short*)(ws + OFF_W2FH);
    unsigned short* W2fl = (unsigned short*)(ws + OFF_W2FL);
    int*   jlist = (int*)(ws + OFF_JLIST);
    int*   jcnt  = (int*)(ws + OFF_JCNT);

    float* out = (float*)d_out;

    dim3 g1(AA, BB);
    ddc_features<<<g1, 64, 0, stream>>>(X, mask, bW1, bb1, bW2, bb2, bW3, bb3,
                                        pW1, pb1, pW2,
                                        hi_p, hjW, baseu, W2fh, W2fl,
                                        jlist, jcnt);
    dim3 g2(GXDIM, BB);
    ddc_pairs_mfma<<<g2, 256, 0, stream>>>(hi_p, hjW, baseu, jlist, jcnt,
                                           W2fh, W2fl, pb2, pW3, pb3, util);
    ddc_softmax<<<BB, 64, 0, stream>>>(util, mask, out);
}